// Round 10
// baseline (344.326 us; speedup 1.0000x reference)
//
#include <hip/hip_runtime.h>
#include <hip/hip_bf16.h>

#define S_LEN 1024
#define DM 256
#define NTOK 32768

typedef __attribute__((ext_vector_type(8))) short short8;
typedef __attribute__((ext_vector_type(4))) short s16x4;
typedef __attribute__((ext_vector_type(4))) float f32x4;

__device__ __forceinline__ float bf2f(unsigned short u) {
    return __uint_as_float(((unsigned int)u) << 16);
}
__device__ __forceinline__ unsigned short f2bf(float f) {
    unsigned int x = __float_as_uint(f);
    return (unsigned short)((x + 0x7fffu + ((x >> 16) & 1u)) >> 16);  // RNE
}

// ---- bf16 weight convert (1 MB/dir x 2 layers) -------------------------
__global__ void convert_w_kernel(const float* __restrict__ WF,
                                 const float* __restrict__ WB,
                                 short* __restrict__ WbF,
                                 short* __restrict__ WbB) {
    int dir = blockIdx.y;
    const float* src = dir ? WB : WF;
    short* dst = dir ? WbB : WbF;
    int idx = blockIdx.x * blockDim.x + threadIdx.x;  // 65536 threads x 8
    const float4* p = (const float4*)src + (size_t)idx * 2;
    float4 a = p[0], b = p[1];
    short8 v;
    v[0] = (short)f2bf(a.x); v[1] = (short)f2bf(a.y);
    v[2] = (short)f2bf(a.z); v[3] = (short)f2bf(a.w);
    v[4] = (short)f2bf(b.x); v[5] = (short)f2bf(b.y);
    v[6] = (short)f2bf(b.z); v[7] = (short)f2bf(b.w);
    ((short8*)dst)[idx] = v;
}

// ---- per-wave GEMM slice (32x64x256) + highway epilogue ----------------
// 16 waves: rg = wave>>3 picks 32-row group, cg = wave&7 picks 32 nl cols
// (+ paired 32 gate cols at +256). acc[2][4] = 32 regs -> spill-free at
// the 128-reg (1024,4) budget.
__device__ __forceinline__ void gemm_hw(const short* src, short* dst,
                                        const short* __restrict__ W,
                                        const float* __restrict__ bias,
                                        int rg, int cg, int l) {
    int krow = l >> 4;
    int lc = l & 15;
    int cb0 = cg * 32;
    int r0 = rg * 32;

    const short* w0 = W + (size_t)(cb0 + lc) * DM + krow * 8;
    const short* w1 = w0 + 16 * DM;
    const short* w2 = w0 + 256 * DM;
    const short* w3 = w0 + (256 + 16) * DM;

    f32x4 acc[2][4];
    f32x4 zero = {0.f, 0.f, 0.f, 0.f};
#pragma unroll
    for (int i = 0; i < 2; i++)
#pragma unroll
        for (int j = 0; j < 4; j++) acc[i][j] = zero;

#pragma unroll
    for (int kk = 0; kk < 8; kk++) {
        short8 bfr0 = *(const short8*)(w0 + kk * 32);
        short8 bfr1 = *(const short8*)(w1 + kk * 32);
        short8 bfr2 = *(const short8*)(w2 + kk * 32);
        short8 bfr3 = *(const short8*)(w3 + kk * 32);
        int k = kk * 32 + krow * 8;
        int row0 = r0 + lc;
        int row1 = r0 + 16 + lc;
        short8 a0 = *(const short8*)(src + row0 * DM + (((k >> 3) ^ (row0 & 7)) << 3));
        short8 a1 = *(const short8*)(src + row1 * DM + (((k >> 3) ^ (row1 & 7)) << 3));
        acc[0][0] = __builtin_amdgcn_mfma_f32_16x16x32_bf16(a0, bfr0, acc[0][0], 0, 0, 0);
        acc[0][1] = __builtin_amdgcn_mfma_f32_16x16x32_bf16(a0, bfr1, acc[0][1], 0, 0, 0);
        acc[0][2] = __builtin_amdgcn_mfma_f32_16x16x32_bf16(a0, bfr2, acc[0][2], 0, 0, 0);
        acc[0][3] = __builtin_amdgcn_mfma_f32_16x16x32_bf16(a0, bfr3, acc[0][3], 0, 0, 0);
        acc[1][0] = __builtin_amdgcn_mfma_f32_16x16x32_bf16(a1, bfr0, acc[1][0], 0, 0, 0);
        acc[1][1] = __builtin_amdgcn_mfma_f32_16x16x32_bf16(a1, bfr1, acc[1][1], 0, 0, 0);
        acc[1][2] = __builtin_amdgcn_mfma_f32_16x16x32_bf16(a1, bfr2, acc[1][2], 0, 0, 0);
        acc[1][3] = __builtin_amdgcn_mfma_f32_16x16x32_bf16(a1, bfr3, acc[1][3], 0, 0, 0);
    }

    // epilogue: C row = (lane>>4)*4 + reg (within 16-block), col = lane&15
#pragma unroll
    for (int mf = 0; mf < 2; mf++) {
#pragma unroll
        for (int nfp = 0; nfp < 2; nfp++) {
            int e = cb0 + nfp * 16 + lc;
            float be = bias[e];
            float bg = bias[e + 256];
#pragma unroll
            for (int r = 0; r < 4; r++) {
                int trow = r0 + mf * 16 + krow * 4 + r;
                int sx = trow * DM + (((e >> 3) ^ (trow & 7)) << 3) + (e & 7);
                float xe = bf2f((unsigned short)src[sx]);
                float nlv = acc[mf][nfp][r] + be;
                float gv = acc[mf][nfp + 2][r] + bg;
                float g = 1.0f / (1.0f + __expf(-gv));
                float y = g * xe + (1.0f - g) * fmaxf(nlv, 0.0f);
                dst[sx] = (short)f2bf(y);
            }
        }
    }
}

// ---- fused per-layer kernel: taps -> hw1 -> hw2 -> coalesced writeout --
// grid (512, 2): 64-token tiles x direction. 1024 threads (16 waves).
// LDS ping-pong: taps->As; hw1: As->Bs; hw2: Bs->As; writeout from As.
template <int IN_F32, int LAST>
__global__ __launch_bounds__(1024, 4)
void layer_kernel(const void* xinF_, const void* xinB_,
                  const float* __restrict__ fpad, const float* __restrict__ bpad,
                  const float* __restrict__ fw5, const float* __restrict__ bw5,
                  const short* __restrict__ WF_, const short* __restrict__ WB_,
                  const float* __restrict__ bF_, const float* __restrict__ bB_,
                  short* __restrict__ xoutF, short* __restrict__ xoutB,
                  float* __restrict__ outp) {
    int dir = blockIdx.y;
    const void* xin = dir ? xinB_ : xinF_;
    const short* W = dir ? WB_ : WF_;
    const float* bias = dir ? bB_ : bF_;
    short* xout = dir ? xoutB : xoutF;
    const float* pad = dir ? bpad : fpad;
    const float* w5g = dir ? bw5 : fw5;
    int ch0 = dir ? 256 : 0;

    __shared__ __align__(16) short As[64 * DM];  // 32 KB, XOR-swizzled (16B chunk ^ row&7)
    __shared__ __align__(16) short Bs[64 * DM];  // 32 KB

    int tid = threadIdx.x;
    int wv = tid >> 6;
    int l = tid & 63;
    int rg = wv >> 3;
    int cg = wv & 7;
    int t0 = blockIdx.x * 64;

    float wj5[5];
#pragma unroll
    for (int j = 0; j < 5; j++) wj5[j] = w5g[j];

    // ---- phase 1: 5-tap conv directly into swizzled As ----
#pragma unroll
    for (int p = 0; p < 2; p++) {
        int pos = p * 1024 + tid;      // 2048 (row, 16B-chunk) positions
        int row = pos >> 5;
        int c = pos & 31;
        int d0 = c << 3;
        int tg = t0 + row;
        int s = tg & (S_LEN - 1);
        float a8[8];
#pragma unroll
        for (int i = 0; i < 8; i++) a8[i] = 0.0f;
#pragma unroll
        for (int j = 0; j < 5; j++) {
            float wj = wj5[j];
            bool use_pad = (dir == 0) ? (s + j < 4) : (s + j >= S_LEN);
            if (use_pad) {
                const float* pf = (dir == 0) ? (pad + (size_t)(s + j) * DM + d0)
                                             : (pad + (size_t)(s + j - S_LEN) * DM + d0);
                const float4* q = (const float4*)pf;
                float4 a = q[0], b = q[1];
                a8[0] += wj * a.x; a8[1] += wj * a.y; a8[2] += wj * a.z; a8[3] += wj * a.w;
                a8[4] += wj * b.x; a8[5] += wj * b.y; a8[6] += wj * b.z; a8[7] += wj * b.w;
            } else {
                long st = (dir == 0) ? ((long)tg + j - 4) : ((long)tg + j);
                if (IN_F32) {
                    const float4* q = (const float4*)((const float*)xin + st * DM + d0);
                    float4 a = q[0], b = q[1];
                    a8[0] += wj * a.x; a8[1] += wj * a.y; a8[2] += wj * a.z; a8[3] += wj * a.w;
                    a8[4] += wj * b.x; a8[5] += wj * b.y; a8[6] += wj * b.z; a8[7] += wj * b.w;
                } else {
                    short8 v = *(const short8*)((const short*)xin + st * DM + d0);
#pragma unroll
                    for (int i = 0; i < 8; i++) a8[i] += wj * bf2f((unsigned short)v[i]);
                }
            }
        }
        short8 o;
#pragma unroll
        for (int i = 0; i < 8; i++) o[i] = (short)f2bf(a8[i]);
        *(short8*)(As + row * DM + ((c ^ (row & 7)) << 3)) = o;
    }
    __syncthreads();

    // ---- phase 2: highway sub-layer 0: As -> Bs ----
    gemm_hw(As, Bs, W, bias, rg, cg, l);
    __syncthreads();

    // ---- phase 3: highway sub-layer 1: Bs -> As ----
    gemm_hw(Bs, As, W + 512 * DM, bias + 512, rg, cg, l);
    __syncthreads();

    // ---- phase 4: coalesced writeout from As ----
    // fp32 out: 1KB contiguous global store per wave-instr
#pragma unroll
    for (int it = 0; it < 4; it++) {
        int pos = it * 1024 + tid;           // 4096 float4 positions
        int row = pos >> 6;
        int c4 = (pos & 63) << 2;
        int sx = row * DM + (((c4 >> 3) ^ (row & 7)) << 3) + (c4 & 7);
        s16x4 v = *(const s16x4*)(As + sx);
        float4 o;
        o.x = bf2f((unsigned short)v[0]);
        o.y = bf2f((unsigned short)v[1]);
        o.z = bf2f((unsigned short)v[2]);
        o.w = bf2f((unsigned short)v[3]);
        *(float4*)(outp + (size_t)(t0 + row) * 512 + ch0 + c4) = o;
    }
    if (!LAST) {
        // bf16 state: 512B contiguous per row
#pragma unroll
        for (int it = 0; it < 2; it++) {
            int pos = it * 1024 + tid;       // 2048 short8 positions
            int row = pos >> 5;
            int c8 = (pos & 31) << 3;
            int sx = row * DM + (((c8 >> 3) ^ (row & 7)) << 3);
            short8 v = *(const short8*)(As + sx);
            *(short8*)(xout + (size_t)(t0 + row) * DM + c8) = v;
        }
    }
}

extern "C" void kernel_launch(void* const* d_in, const int* in_sizes, int n_in,
                              void* d_out, int out_size, void* d_ws, size_t ws_size,
                              hipStream_t stream) {
    const float* inputs = (const float*)d_in[0];
    const float* fwd_pad = (const float*)d_in[1];
    const float* bwd_pad = (const float*)d_in[2];
    const float* fwd_w = (const float*)d_in[3];
    const float* bwd_w = (const float*)d_in[4];
    const float* fwd_hw_W = (const float*)d_in[5];
    const float* fwd_hw_b = (const float*)d_in[6];
    const float* bwd_hw_W = (const float*)d_in[7];
    const float* bwd_hw_b = (const float*)d_in[8];
    float* out = (float*)d_out;

    const size_t XN = (size_t)NTOK * DM;          // 8,388,608 bf16 per state buf
    const size_t WN = (size_t)2 * 2 * 512 * 256;  // per-dir bf16 weight elems
    short* curF = (short*)d_ws;
    short* curB = curF + XN;
    short* WbF = curB + XN;
    short* WbB = WbF + WN;  // total ws: 32 MB state + 4 MB weights

    convert_w_kernel<<<dim3(256, 2), dim3(256), 0, stream>>>(fwd_hw_W, bwd_hw_W, WbF, WbB);

    // layer 0: reads fp32 inputs (both dirs), writes bf16 state + fp32 out
    layer_kernel<1, 0><<<dim3(512, 2), dim3(1024), 0, stream>>>(
        (const void*)inputs, (const void*)inputs,
        fwd_pad, bwd_pad, fwd_w, bwd_w,
        WbF, WbB, fwd_hw_b, bwd_hw_b,
        curF, curB, out);

    // layer 1: reads bf16 state, writes fp32 out only
    layer_kernel<0, 1><<<dim3(512, 2), dim3(1024), 0, stream>>>(
        (const void*)curF, (const void*)curB,
        fwd_pad + 4 * DM, bwd_pad + 4 * DM, fwd_w + 5, bwd_w + 5,
        WbF + 2 * 512 * DM, WbB + 2 * 512 * DM,
        fwd_hw_b + 1024, bwd_hw_b + 1024,
        nullptr, nullptr, out + (size_t)NTOK * 512);
}

// Round 11
// 171.602 us; speedup vs baseline: 2.0065x; 2.0065x over previous
//
#include <hip/hip_runtime.h>
#include <hip/hip_bf16.h>

#define S_LEN 1024
#define DM 256
#define NTOK 32768

typedef __attribute__((ext_vector_type(8))) short short8;
typedef __attribute__((ext_vector_type(4))) short s16x4;
typedef __attribute__((ext_vector_type(4))) float f32x4;

__device__ __forceinline__ float bf2f(unsigned short u) {
    return __uint_as_float(((unsigned int)u) << 16);
}
__device__ __forceinline__ unsigned short f2bf(float f) {
    unsigned int x = __float_as_uint(f);
    return (unsigned short)((x + 0x7fffu + ((x >> 16) & 1u)) >> 16);  // RNE
}
__device__ __forceinline__ void async16(const void* g, void* l) {
    __builtin_amdgcn_global_load_lds(
        (const __attribute__((address_space(1))) void*)g,
        (__attribute__((address_space(3))) void*)l, 16, 0, 0);
}

// ---- bf16 weight convert (1 MB/dir x 2 layers) -------------------------
__global__ void convert_w_kernel(const float* __restrict__ WF,
                                 const float* __restrict__ WB,
                                 short* __restrict__ WbF,
                                 short* __restrict__ WbB) {
    int dir = blockIdx.y;
    const float* src = dir ? WB : WF;
    short* dst = dir ? WbB : WbF;
    int idx = blockIdx.x * blockDim.x + threadIdx.x;  // 65536 threads x 8
    const float4* p = (const float4*)src + (size_t)idx * 2;
    float4 a = p[0], b = p[1];
    short8 v;
    v[0] = (short)f2bf(a.x); v[1] = (short)f2bf(a.y);
    v[2] = (short)f2bf(a.z); v[3] = (short)f2bf(a.w);
    v[4] = (short)f2bf(b.x); v[5] = (short)f2bf(b.y);
    v[6] = (short)f2bf(b.z); v[7] = (short)f2bf(b.w);
    ((short8*)dst)[idx] = v;
}

// ---- stage W K-slice [512 rows][32 K] into LDS (32 KB), swizzled -------
// LDS layout: 32 row-groups (rg=row>>4) x 1024B. slot16(rg,lc,krw) holds
// W[rg*16+lc][ks*32 + (krw^(lc&3))*8 .. +8]. Read at krw=krow^(lc&3)
// -> balanced 8 words/bank (conflict-free). Linear LDS dest, permuted
// global source (both-sides rule, m104).
__device__ __forceinline__ void stage_w(const short* __restrict__ Wk, short* Ws, int tid) {
#pragma unroll
    for (int r = 0; r < 4; r++) {
        int slot = r * 512 + tid;
        int rg = slot >> 6;
        int u = slot & 63;
        int lc = u >> 2;
        int krw = u & 3;
        int kg = krw ^ (lc & 3);
        const short* g = Wk + (size_t)(rg * 16 + lc) * DM + kg * 8;
        async16((const void*)g, (void*)(Ws + slot * 8));
    }
}

// ---- one K-step (K=32) of the 64x512 GEMM, both operands from LDS ------
__device__ __forceinline__ void gemm_step(const short* As_, const short* Ws,
                                          f32x4 acc[4][4], int ks, int wv, int l) {
    int krow = l >> 4, lc = l & 15;
    int k8 = ks * 4 + krow;
    int wq = lc * 4 + (krow ^ (lc & 3));
    int rgb = wv * 2;
    short8 a[4], w[4];
#pragma unroll
    for (int mf = 0; mf < 4; mf++) {
        int row = mf * 16 + lc;
        a[mf] = *(const short8*)(As_ + row * DM + ((k8 ^ (row & 7)) << 3));
    }
    w[0] = *(const short8*)(Ws + (rgb * 64 + wq) * 8);
    w[1] = *(const short8*)(Ws + ((rgb + 1) * 64 + wq) * 8);
    w[2] = *(const short8*)(Ws + ((rgb + 16) * 64 + wq) * 8);
    w[3] = *(const short8*)(Ws + ((rgb + 17) * 64 + wq) * 8);
#pragma unroll
    for (int mf = 0; mf < 4; mf++)
#pragma unroll
        for (int nf = 0; nf < 4; nf++)
            acc[mf][nf] = __builtin_amdgcn_mfma_f32_16x16x32_bf16(
                a[mf], w[nf], acc[mf][nf], 0, 0, 0);
}

// ---- highway epilogue: y = g*x + (1-g)*relu(nl), in place on As --------
__device__ __forceinline__ void hw_epilogue(f32x4 acc[4][4], const float* __restrict__ bias,
                                            short* As_, int wv, int l) {
    int cb0 = wv * 32, krow = l >> 4, lc = l & 15;
#pragma unroll
    for (int mf = 0; mf < 4; mf++) {
#pragma unroll
        for (int nfp = 0; nfp < 2; nfp++) {
            int e = cb0 + nfp * 16 + lc;
            float be = bias[e];
            float bg = bias[e + 256];
#pragma unroll
            for (int r = 0; r < 4; r++) {
                int trow = mf * 16 + krow * 4 + r;
                int sx = trow * DM + (((e >> 3) ^ (trow & 7)) << 3) + (e & 7);
                float xe = bf2f((unsigned short)As_[sx]);
                float nlv = acc[mf][nfp][r] + be;
                float gv = acc[mf][nfp + 2][r] + bg;
                float g = 1.0f / (1.0f + __expf(-gv));
                float y = g * xe + (1.0f - g) * fmaxf(nlv, 0.0f);
                As_[sx] = (short)f2bf(y);
            }
        }
    }
}

// ---- fused per-layer kernel: taps -> hw1 -> hw2 -> coalesced writeout --
// grid (512, 2): 64-token tiles x direction. 512 threads (8 waves).
// LDS: As 32KB (activations, in-place through all phases) + Ws 32KB
// (W K-slice, restaged 8x per GEMM) = 64KB -> 2 blocks/CU.
template <int IN_F32, int LAST>
__global__ __launch_bounds__(512, 4)
void layer_kernel(const void* xinF_, const void* xinB_,
                  const float* __restrict__ fpad, const float* __restrict__ bpad,
                  const float* __restrict__ fw5, const float* __restrict__ bw5,
                  const short* __restrict__ WF_, const short* __restrict__ WB_,
                  const float* __restrict__ bF_, const float* __restrict__ bB_,
                  short* __restrict__ xoutF, short* __restrict__ xoutB,
                  float* __restrict__ outp) {
    int dir = blockIdx.y;
    const void* xin = dir ? xinB_ : xinF_;
    const short* W = dir ? WB_ : WF_;
    const float* bias = dir ? bB_ : bF_;
    short* xout = dir ? xoutB : xoutF;
    const float* pad = dir ? bpad : fpad;
    const float* w5g = dir ? bw5 : fw5;
    int ch0 = dir ? 256 : 0;

    __shared__ __align__(16) short As[64 * DM];   // 32 KB
    __shared__ __align__(16) short Ws[512 * 32];  // 32 KB

    int tid = threadIdx.x;
    int wv = tid >> 6;
    int l = tid & 63;
    int t0 = blockIdx.x * 64;

    // issue GEMM1 slice-0 staging early: overlaps the taps phase
    stage_w(W, Ws, tid);

    float wj5[5];
#pragma unroll
    for (int j = 0; j < 5; j++) wj5[j] = w5g[j];

    // ---- phase 1: 5-tap conv directly into swizzled As ----
#pragma unroll
    for (int p = 0; p < 4; p++) {
        int pos = p * 512 + tid;       // 2048 (row, 16B-chunk) positions
        int row = pos >> 5;
        int c = pos & 31;
        int d0 = c << 3;
        int tg = t0 + row;
        int s = tg & (S_LEN - 1);
        float a8[8];
#pragma unroll
        for (int i = 0; i < 8; i++) a8[i] = 0.0f;
#pragma unroll
        for (int j = 0; j < 5; j++) {
            float wj = wj5[j];
            bool use_pad = (dir == 0) ? (s + j < 4) : (s + j >= S_LEN);
            if (use_pad) {
                const float* pf = (dir == 0) ? (pad + (size_t)(s + j) * DM + d0)
                                             : (pad + (size_t)(s + j - S_LEN) * DM + d0);
                const float4* q = (const float4*)pf;
                float4 a = q[0], b = q[1];
                a8[0] += wj * a.x; a8[1] += wj * a.y; a8[2] += wj * a.z; a8[3] += wj * a.w;
                a8[4] += wj * b.x; a8[5] += wj * b.y; a8[6] += wj * b.z; a8[7] += wj * b.w;
            } else {
                long st = (dir == 0) ? ((long)tg + j - 4) : ((long)tg + j);
                if (IN_F32) {
                    const float4* q = (const float4*)((const float*)xin + st * DM + d0);
                    float4 a = q[0], b = q[1];
                    a8[0] += wj * a.x; a8[1] += wj * a.y; a8[2] += wj * a.z; a8[3] += wj * a.w;
                    a8[4] += wj * b.x; a8[5] += wj * b.y; a8[6] += wj * b.z; a8[7] += wj * b.w;
                } else {
                    short8 v = *(const short8*)((const short*)xin + st * DM + d0);
#pragma unroll
                    for (int i = 0; i < 8; i++) a8[i] += wj * bf2f((unsigned short)v[i]);
                }
            }
        }
        short8 o;
#pragma unroll
        for (int i = 0; i < 8; i++) o[i] = (short)f2bf(a8[i]);
        *(short8*)(As + row * DM + ((c ^ (row & 7)) << 3)) = o;
    }

    f32x4 acc[4][4];
    f32x4 zero = {0.f, 0.f, 0.f, 0.f};
#pragma unroll
    for (int i = 0; i < 4; i++)
#pragma unroll
        for (int j = 0; j < 4; j++) acc[i][j] = zero;

    // ---- phase 2: GEMM1 over 8 K-slices, W from LDS ----
#pragma unroll 1
    for (int ks = 0; ks < 8; ks++) {
        asm volatile("s_waitcnt vmcnt(0)" ::: "memory");
        __syncthreads();                       // Ws[ks] (and As on ks=0) ready
        gemm_step(As, Ws, acc, ks, wv, l);
        __syncthreads();                       // all Ws[ks] reads done
        if (ks < 7) stage_w(W + (ks + 1) * 32, Ws, tid);
    }
    // GEMM2 slice-0 staging overlaps epilogue1
    stage_w(W + 512 * DM, Ws, tid);
    hw_epilogue(acc, bias, As, wv, l);         // in place: per-lane own slots

#pragma unroll
    for (int i = 0; i < 4; i++)
#pragma unroll
        for (int j = 0; j < 4; j++) acc[i][j] = zero;

    // ---- phase 3: GEMM2 ----
#pragma unroll 1
    for (int ks = 0; ks < 8; ks++) {
        asm volatile("s_waitcnt vmcnt(0)" ::: "memory");
        __syncthreads();                       // Ws ready; epilogue1 As writes visible
        gemm_step(As, Ws, acc, ks, wv, l);
        __syncthreads();
        if (ks < 7) stage_w(W + 512 * DM + (ks + 1) * 32, Ws, tid);
    }
    hw_epilogue(acc, bias + 512, As, wv, l);
    __syncthreads();

    // ---- phase 4: coalesced writeout from As ----
#pragma unroll
    for (int it = 0; it < 8; it++) {
        int pos = it * 512 + tid;            // 4096 float4 positions
        int row = pos >> 6;
        int c4 = (pos & 63) << 2;
        int sx = row * DM + (((c4 >> 3) ^ (row & 7)) << 3) + (c4 & 7);
        s16x4 v = *(const s16x4*)(As + sx);
        float4 o;
        o.x = bf2f((unsigned short)v[0]);
        o.y = bf2f((unsigned short)v[1]);
        o.z = bf2f((unsigned short)v[2]);
        o.w = bf2f((unsigned short)v[3]);
        *(float4*)(outp + (size_t)(t0 + row) * 512 + ch0 + c4) = o;
    }
    if (!LAST) {
#pragma unroll
        for (int it = 0; it < 4; it++) {
            int pos = it * 512 + tid;        // 2048 short8 positions
            int row = pos >> 5;
            int c8 = (pos & 31) << 3;
            int sx = row * DM + (((c8 >> 3) ^ (row & 7)) << 3);
            short8 v = *(const short8*)(As + sx);
            *(short8*)(xout + (size_t)(t0 + row) * DM + c8) = v;
        }
    }
}

extern "C" void kernel_launch(void* const* d_in, const int* in_sizes, int n_in,
                              void* d_out, int out_size, void* d_ws, size_t ws_size,
                              hipStream_t stream) {
    const float* inputs = (const float*)d_in[0];
    const float* fwd_pad = (const float*)d_in[1];
    const float* bwd_pad = (const float*)d_in[2];
    const float* fwd_w = (const float*)d_in[3];
    const float* bwd_w = (const float*)d_in[4];
    const float* fwd_hw_W = (const float*)d_in[5];
    const float* fwd_hw_b = (const float*)d_in[6];
    const float* bwd_hw_W = (const float*)d_in[7];
    const float* bwd_hw_b = (const float*)d_in[8];
    float* out = (float*)d_out;

    const size_t XN = (size_t)NTOK * DM;          // 8,388,608 bf16 per state buf
    const size_t WN = (size_t)2 * 2 * 512 * 256;  // per-dir bf16 weight elems
    short* curF = (short*)d_ws;
    short* curB = curF + XN;
    short* WbF = curB + XN;
    short* WbB = WbF + WN;  // total ws: 32 MB state + 4 MB weights

    convert_w_kernel<<<dim3(256, 2), dim3(256), 0, stream>>>(fwd_hw_W, bwd_hw_W, WbF, WbB);

    // layer 0: reads fp32 inputs (both dirs), writes bf16 state + fp32 out
    layer_kernel<1, 0><<<dim3(512, 2), dim3(512), 0, stream>>>(
        (const void*)inputs, (const void*)inputs,
        fwd_pad, bwd_pad, fwd_w, bwd_w,
        WbF, WbB, fwd_hw_b, bwd_hw_b,
        curF, curB, out);

    // layer 1: reads bf16 state, writes fp32 out only
    layer_kernel<0, 1><<<dim3(512, 2), dim3(512), 0, stream>>>(
        (const void*)curF, (const void*)curB,
        fwd_pad + 4 * DM, bwd_pad + 4 * DM, fwd_w + 5, bwd_w + 5,
        WbF + 2 * 512 * DM, WbB + 2 * 512 * DM,
        fwd_hw_b + 1024, bwd_hw_b + 1024,
        nullptr, nullptr, out + (size_t)NTOK * 512);
}